// Round 10
// baseline (728.230 us; speedup 1.0000x reference)
//
#include <hip/hip_runtime.h>

#define D_MODEL 1024
#define LSEQ    8192
#define NC      8192            // complex FFT size = (2*L)/2
#define PI_F    3.14159265358979323846f
#define TWO_PI_OVER_N 3.8349519697141029e-4f   // 2*pi/16384
#define R2F  0.70710678118654752440f           // cos(pi/4)
#define C18F 0.92387953251128675613f           // cos(pi/8)
#define S18F 0.38268343236508977173f           // sin(pi/8)

// Extended XOR swizzle on LDS float2 index (bijective on [0,8192)).
__device__ __forceinline__ int sw(int p) { return p ^ ((p >> 7) & 15) ^ ((p >> 3) & 7); }
__device__ __forceinline__ int rev13(int x) { return (int)(__brev((unsigned)x) >> 19); }
__device__ __forceinline__ float2 cmulf(float2 a, float2 b) {
    return make_float2(a.x*b.x - a.y*b.y, a.x*b.y + a.y*b.x);
}

// ---- radix-2 butterflies -------------------------------------------------
__device__ __forceinline__ void bf_dif(float2& a, float2& b, float c, float s) {
    float tx = a.x - b.x, ty = a.y - b.y;
    a.x += b.x; a.y += b.y;
    b.x = tx*c - ty*s; b.y = tx*s + ty*c;
}
__device__ __forceinline__ void bf_dif1(float2& a, float2& b) {        // w = 1
    float tx = a.x - b.x, ty = a.y - b.y;
    a.x += b.x; a.y += b.y;
    b.x = tx; b.y = ty;
}
__device__ __forceinline__ void bf_dif_mi(float2& a, float2& b) {      // w = -i
    float tx = a.x - b.x, ty = a.y - b.y;
    a.x += b.x; a.y += b.y;
    b.x = ty; b.y = -tx;
}
__device__ __forceinline__ void bf_dit(float2& a, float2& b, float c, float s) {
    float bx = b.x*c - b.y*s, by = b.x*s + b.y*c;
    b.x = a.x - bx; b.y = a.y - by;
    a.x += bx; a.y += by;
}
__device__ __forceinline__ void bf_dit1(float2& a, float2& b) {        // w = 1
    float bx = b.x, by = b.y;
    b.x = a.x - bx; b.y = a.y - by;
    a.x += bx; a.y += by;
}
__device__ __forceinline__ void bf_dit_pi(float2& a, float2& b) {      // w = +i
    float bx = -b.y, by = b.x;
    b.x = a.x - bx; b.y = a.y - by;
    a.x += bx; a.y += by;
}
// DIT a-output only: a' = a + w*b   (final level where b' is dead)
__device__ __forceinline__ void bf_dit_a(float2& a, float2 b, float c, float s) {
    a.x += b.x*c - b.y*s; a.y += b.x*s + b.y*c;
}

// === conv kernel: 1024 threads, each owns 8 elements; every pass is a ======
// === single loop-free body. LDS padded to 96 KB so only ONE block/CU fits: =
// === the compiler's VGPR budget is LDS-occupancy-driven (64 KB -> 2 blocks =
// === -> 8 waves/EU -> 64-VGPR budget -> ~2 GB/dispatch spill in r6-r9; =====
// === 96 KB -> 1 block -> 4 waves/EU -> 128-VGPR budget -> no spill). =======

// ---- fused forward pass: DIF levels H, H/2, H/4 (H in {512, 64}) ---------
template<int H>
__device__ __forceinline__ void fwd_pass8(float2* s, int tid) {
    const float astep = -PI_F / (float)H;
    int q    = tid & (H/4 - 1);
    int base = (tid - q) * 8 + q;               // block*2H + q
    float2 v[8];
    #pragma unroll
    for (int m = 0; m < 8; ++m) v[m] = s[sw(base + m*(H/4))];
    float a = astep * (float)q;
    float c1,s1,c2,s2,c4,s4;
    __sincosf(a,     &s1, &c1);
    __sincosf(a+a,   &s2, &c2);
    __sincosf(4.f*a, &s4, &c4);
    // level H: pairs (m, m+4), w = e^{ia} * e^{-i pi m/4}
    bf_dif(v[0], v[4], c1, s1);
    bf_dif(v[1], v[5], R2F*(c1+s1), R2F*(s1-c1));
    bf_dif(v[2], v[6], s1, -c1);
    bf_dif(v[3], v[7], R2F*(s1-c1), -R2F*(c1+s1));
    // level H/2: pairs (m, m+2); odd pairs get extra *(-i)
    bf_dif(v[0], v[2], c2, s2);  bf_dif(v[4], v[6], c2, s2);
    bf_dif(v[1], v[3], s2, -c2); bf_dif(v[5], v[7], s2, -c2);
    // level H/4: all pairs (m, m+1), w = e^{i4a}
    bf_dif(v[0], v[1], c4, s4); bf_dif(v[2], v[3], c4, s4);
    bf_dif(v[4], v[5], c4, s4); bf_dif(v[6], v[7], c4, s4);
    #pragma unroll
    for (int m = 0; m < 8; ++m) s[sw(base + m*(H/4))] = v[m];
}

// ---- DIF levels 8,4,2,1 on a contiguous 16-block (all twiddles const) ----
__device__ __forceinline__ void dif16(float2* v) {
    bf_dif1 (v[0], v[8]);
    bf_dif  (v[1], v[9],   C18F, -S18F);
    bf_dif  (v[2], v[10],  R2F,  -R2F);
    bf_dif  (v[3], v[11],  S18F, -C18F);
    bf_dif_mi(v[4], v[12]);
    bf_dif  (v[5], v[13], -S18F, -C18F);
    bf_dif  (v[6], v[14], -R2F,  -R2F);
    bf_dif  (v[7], v[15], -C18F, -S18F);
    bf_dif1 (v[0], v[4]);              bf_dif1 (v[8],  v[12]);
    bf_dif  (v[1], v[5],  R2F, -R2F);  bf_dif  (v[9],  v[13],  R2F, -R2F);
    bf_dif_mi(v[2], v[6]);             bf_dif_mi(v[10], v[14]);
    bf_dif  (v[3], v[7], -R2F, -R2F);  bf_dif  (v[11], v[15], -R2F, -R2F);
    bf_dif1 (v[0], v[2]); bf_dif1 (v[4], v[6]); bf_dif1 (v[8], v[10]); bf_dif1 (v[12], v[14]);
    bf_dif_mi(v[1], v[3]); bf_dif_mi(v[5], v[7]); bf_dif_mi(v[9], v[11]); bf_dif_mi(v[13], v[15]);
    bf_dif1(v[0], v[1]); bf_dif1(v[2], v[3]);  bf_dif1(v[4], v[5]);  bf_dif1(v[6], v[7]);
    bf_dif1(v[8], v[9]); bf_dif1(v[10],v[11]); bf_dif1(v[12],v[13]); bf_dif1(v[14],v[15]);
}

// ---- full forward FFT: global (zero-padded) -> LDS, bit-reversed output --
__device__ __forceinline__ void fwd_fft(float2* s, int tid, const float2* __restrict__ g) {
    {
        const float astep = -PI_F / 4096.0f;
        int q = tid;                            // 0..1023
        float2 v[8];
        #pragma unroll
        for (int m = 0; m < 4; ++m) v[m] = g[q + m*1024];
        float a = astep * (float)q;
        float c1,s1,c2,s2,c4,s4;
        __sincosf(a,     &s1, &c1);
        __sincosf(a+a,   &s2, &c2);
        __sincosf(4.f*a, &s4, &c4);
        // level 4096 vs zero upper half: v[m+4] = v[m] * (e^{ia} e^{-i pi m/4})
        float wc, ws;
        wc = c1;            ws = s1;             v[4] = make_float2(v[0].x*wc - v[0].y*ws, v[0].x*ws + v[0].y*wc);
        wc = R2F*(c1+s1);   ws = R2F*(s1-c1);    v[5] = make_float2(v[1].x*wc - v[1].y*ws, v[1].x*ws + v[1].y*wc);
        wc = s1;            ws = -c1;            v[6] = make_float2(v[2].x*wc - v[2].y*ws, v[2].x*ws + v[2].y*wc);
        wc = R2F*(s1-c1);   ws = -R2F*(c1+s1);   v[7] = make_float2(v[3].x*wc - v[3].y*ws, v[3].x*ws + v[3].y*wc);
        // level 2048
        bf_dif(v[0], v[2], c2, s2);  bf_dif(v[4], v[6], c2, s2);
        bf_dif(v[1], v[3], s2, -c2); bf_dif(v[5], v[7], s2, -c2);
        // level 1024
        bf_dif(v[0], v[1], c4, s4); bf_dif(v[2], v[3], c4, s4);
        bf_dif(v[4], v[5], c4, s4); bf_dif(v[6], v[7], c4, s4);
        #pragma unroll
        for (int m = 0; m < 8; ++m) s[sw(q + m*1024)] = v[m];
    }
    __syncthreads();
    fwd_pass8<512>(s, tid);
    __syncthreads();
    fwd_pass8<64>(s, tid);
    __syncthreads();
    if (tid < 512) {                            // levels 8,4,2,1 (16/thread)
        int base = tid << 4;
        float2 v[16];
        #pragma unroll
        for (int m = 0; m < 16; ++m) v[m] = s[sw(base + m)];
        dif16(v);
        #pragma unroll
        for (int m = 0; m < 16; ++m) s[sw(base + m)] = v[m];
    }
}

// ---- DIT levels 1,2,4,8 on a contiguous 16-block (const twiddles, +i) ----
__device__ __forceinline__ void dit16(float2* v) {
    bf_dit1(v[0], v[1]); bf_dit1(v[2], v[3]);  bf_dit1(v[4], v[5]);  bf_dit1(v[6], v[7]);
    bf_dit1(v[8], v[9]); bf_dit1(v[10],v[11]); bf_dit1(v[12],v[13]); bf_dit1(v[14],v[15]);
    bf_dit1 (v[0], v[2]); bf_dit_pi(v[1], v[3]);
    bf_dit1 (v[4], v[6]); bf_dit_pi(v[5], v[7]);
    bf_dit1 (v[8], v[10]); bf_dit_pi(v[9], v[11]);
    bf_dit1 (v[12],v[14]); bf_dit_pi(v[13],v[15]);
    bf_dit1 (v[0], v[4]);             bf_dit1 (v[8],  v[12]);
    bf_dit  (v[1], v[5],  R2F, R2F);  bf_dit  (v[9],  v[13],  R2F, R2F);
    bf_dit_pi(v[2], v[6]);            bf_dit_pi(v[10], v[14]);
    bf_dit  (v[3], v[7], -R2F, R2F);  bf_dit  (v[11], v[15], -R2F, R2F);
    bf_dit1 (v[0], v[8]);
    bf_dit  (v[1], v[9],   C18F, S18F);
    bf_dit  (v[2], v[10],  R2F,  R2F);
    bf_dit  (v[3], v[11],  S18F, C18F);
    bf_dit_pi(v[4], v[12]);
    bf_dit  (v[5], v[13], -S18F, C18F);
    bf_dit  (v[6], v[14], -R2F,  R2F);
    bf_dit  (v[7], v[15], -C18F, S18F);
}

// ---- fused inverse pass: DIT levels H, 2H, 4H (H in {16, 128}) -----------
template<int H>
__device__ __forceinline__ void inv_pass8(float2* s, int tid) {
    const float bstep = PI_F / (float)(4*H);
    int q    = tid & (H - 1);
    int base = (tid - q) * 8 + q;               // block*8H + q
    float2 v[8];
    #pragma unroll
    for (int m = 0; m < 8; ++m) v[m] = s[sw(base + m*H)];
    float bb = bstep * (float)q;
    float cb,sb,c2,s2,c4,s4;
    __sincosf(bb,      &sb, &cb);
    __sincosf(bb+bb,   &s2, &c2);
    __sincosf(4.f*bb,  &s4, &c4);
    bf_dit(v[0],v[1],c4,s4); bf_dit(v[2],v[3],c4,s4);
    bf_dit(v[4],v[5],c4,s4); bf_dit(v[6],v[7],c4,s4);
    bf_dit(v[0],v[2], c2,s2);  bf_dit(v[4],v[6], c2,s2);
    bf_dit(v[1],v[3],-s2,c2);  bf_dit(v[5],v[7],-s2,c2);
    bf_dit(v[0],v[4],  cb, sb);
    bf_dit(v[1],v[5],  R2F*(cb-sb), R2F*(sb+cb));
    bf_dit(v[2],v[6], -sb, cb);
    bf_dit(v[3],v[7], -R2F*(sb+cb), R2F*(cb-sb));
    #pragma unroll
    for (int m = 0; m < 8; ++m) s[sw(base + m*H)] = v[m];
}

// ---- last inverse pass (levels 1024,2048,4096) fused with epilogue -------
// Only complex n in [0,4096) survive (= m 0..3); store MUST stop at m<4.
__device__ __forceinline__ void inv_last_out(const float2* s, int tid,
                                             const float2* __restrict__ xv,
                                             float2* __restrict__ ov, float Dd) {
    const float bstep = PI_F / 4096.0f;
    int q = tid;                                // single 8192-block
    float2 v[8];
    #pragma unroll
    for (int m = 0; m < 8; ++m) v[m] = s[sw(q + m*1024)];
    float bb = bstep * (float)q;
    float cb,sb,c2,s2,c4,s4;
    __sincosf(bb,      &sb, &cb);
    __sincosf(bb+bb,   &s2, &c2);
    __sincosf(4.f*bb,  &s4, &c4);
    bf_dit(v[0],v[1],c4,s4); bf_dit(v[2],v[3],c4,s4);
    bf_dit(v[4],v[5],c4,s4); bf_dit(v[6],v[7],c4,s4);
    bf_dit(v[0],v[2], c2,s2);  bf_dit(v[4],v[6], c2,s2);
    bf_dit(v[1],v[3],-s2,c2);  bf_dit(v[5],v[7],-s2,c2);
    bf_dit_a(v[0], v[4],  cb, sb);
    bf_dit_a(v[1], v[5],  R2F*(cb-sb), R2F*(sb+cb));
    bf_dit_a(v[2], v[6], -sb, cb);
    bf_dit_a(v[3], v[7], -R2F*(sb+cb), R2F*(cb-sb));
    #pragma unroll
    for (int m = 0; m < 4; ++m) {
        int n = q + m*1024;
        float2 xx = xv[n];
        ov[n] = make_float2(v[m].x + xx.x * Dd, v[m].y + xx.y * Dd);
    }
}

// ---- spectral helpers ----------------------------------------------------
__device__ __forceinline__ void k_unpack(const float2* s, int k, float invN,
                                         float2& Kkj, float2& Kmj) {
    int m = NC - k;
    float2 Ck = s[sw(rev13(k))], Cm = s[sw(rev13(m))];
    float sn, cs;
    __sincosf(TWO_PI_OVER_N * (float)k, &sn, &cs);   // w = (cs,-sn)
    float2 E = make_float2(Ck.x + Cm.x, Ck.y - Cm.y); // Ck + conj(Cm)
    float2 O = make_float2(Ck.x - Cm.x, Ck.y + Cm.y); // Ck - conj(Cm)
    float2 WO = make_float2(O.x * cs + O.y * sn, -O.x * sn + O.y * cs); // w*O
    float2 T = make_float2(-WO.y, WO.x);              // i*w*O
    Kkj = make_float2(0.5f * invN * (E.x - T.x),  0.5f * invN * (E.y - T.y));
    Kmj = make_float2(0.5f * invN * (E.x + T.x), -0.5f * invN * (E.y + T.y)); // conj(E+T)/2N
}

__device__ __forceinline__ void mul_one(float2* s, int k, float2 Kkj, float2 Kmj) {
    int m = NC - k;
    int pk = sw(rev13(k)), pm = sw(rev13(m));
    float2 Ck = s[pk], Cm = s[pm];
    float sn, cs;
    __sincosf(TWO_PI_OVER_N * (float)k, &sn, &cs);   // w = (cs,-sn)
    float2 E = make_float2(Ck.x + Cm.x, Ck.y - Cm.y);
    float2 O = make_float2(Ck.x - Cm.x, Ck.y + Cm.y);
    float2 WO = make_float2(O.x * cs + O.y * sn, -O.x * sn + O.y * cs);
    float2 T = make_float2(-WO.y, WO.x);
    float2 Uk = make_float2(0.5f * (E.x - T.x),  0.5f * (E.y - T.y));
    float2 Um = make_float2(0.5f * (E.x + T.x), -0.5f * (E.y + T.y));
    float2 Yk = cmulf(Uk, Kkj);
    float2 Ym = cmulf(Um, Kmj);
    float2 P = make_float2(Yk.x + Ym.x, Yk.y - Ym.y);  // Yk + conj(Ym)
    float2 Q = make_float2(Yk.x - Ym.x, Yk.y + Ym.y);  // Yk - conj(Ym)
    float2 CQ = make_float2(Q.x * cs - Q.y * sn, Q.x * sn + Q.y * cs); // conj(w)*Q
    float2 T2 = make_float2(-CQ.y, CQ.x);              // i*conj(w)*Q
    s[pk] = make_float2(P.x + T2.x, P.y + T2.y);       // Z2[k]
    s[pm] = make_float2(P.x - T2.x, -(P.y - T2.y));    // Z2[m] = conj(P-T2)
}

// ---------------------------------------------------------------------------
// Kernel 1: implicit-filter MLP + output projection + exponential modulation.
// zbuf phase-0 (trig amortized) folded into an A/B ping-pong; batched LDS
// reads; (256,4) caps VGPR at 128; 33.3 KB LDS -> 4 blocks/CU.
// ---------------------------------------------------------------------------
__global__ void __launch_bounds__(256, 4) hyena_filter_k(
    const float* __restrict__ W1, const float* __restrict__ b1,
    const float* __restrict__ freq,
    const float* __restrict__ W2, const float* __restrict__ b2,
    const float* __restrict__ W3, const float* __restrict__ b3,
    const float* __restrict__ Wout,
    float* __restrict__ kout)
{
    __shared__ float Abuf[64][65];   // stride 65: (p+o)%32 -> 2-way (free)
    __shared__ float Bbuf[64][65];

    const int tid = threadIdx.x;
    const int pbase = blockIdx.x * 64;

    // phase 0: positional embedding z[p][0..32] -> Abuf (trig amortized)
    for (int idx = tid; idx < 64 * 33; idx += 256) {
        int p = idx & 63, e = idx >> 6;
        int gp = pbase + p;
        float w = 7.6699039394282907e-4f * (float)gp;   // 2*pi*gp/8192
        float val;
        if (e == 0) {
            val = (float)gp / 8191.0f;
        } else if (e < 17) {
            float f = 1.0e-4f + (float)(e - 1) * ((15.0f - 1.0e-4f) / 15.0f);
            val = cosf(f * w);
        } else {
            float f = 1.0e-4f + (float)(e - 17) * ((15.0f - 1.0e-4f) / 15.0f);
            val = -sinf(f * w);
        }
        Abuf[p][e] = val;
    }
    __syncthreads();

    const int p  = tid & 63;                                       // lane-varying
    const int g4 = __builtin_amdgcn_readfirstlane(tid >> 6);       // wave-uniform
    const int ob = g4 * 16;
    const int gp = pbase + p;

    // layer 1: 33 -> 64, A -> B
    {
        float acc[16];
        #pragma unroll
        for (int oo = 0; oo < 16; ++oo) acc[oo] = b1[ob + oo];
        #pragma unroll
        for (int e = 0; e < 33; ++e) {
            float ae = Abuf[p][e];
            const float* wr = W1 + e * 64 + ob;
            #pragma unroll
            for (int oo = 0; oo < 16; ++oo) acc[oo] += ae * wr[oo];
        }
        #pragma unroll
        for (int oo = 0; oo < 16; ++oo) Bbuf[p][ob + oo] = __sinf(freq[ob + oo] * acc[oo]);
    }
    __syncthreads();
    // layer 2: B -> A (old A dead after the L1 barrier)
    {
        float acc[16];
        #pragma unroll
        for (int oo = 0; oo < 16; ++oo) acc[oo] = b2[ob + oo];
        #pragma unroll 1
        for (int eb = 0; eb < 8; ++eb) {
            float hreg[8];
            #pragma unroll
            for (int j = 0; j < 8; ++j) hreg[j] = Bbuf[p][eb * 8 + j];
            #pragma unroll
            for (int j = 0; j < 8; ++j) {
                const float* wr = W2 + (eb * 8 + j) * 64 + ob;
                #pragma unroll
                for (int oo = 0; oo < 16; ++oo) acc[oo] += hreg[j] * wr[oo];
            }
        }
        #pragma unroll
        for (int oo = 0; oo < 16; ++oo) Abuf[p][ob + oo] = __sinf(freq[ob + oo] * acc[oo]);
    }
    __syncthreads();
    // layer 3: A -> B
    {
        float acc[16];
        #pragma unroll
        for (int oo = 0; oo < 16; ++oo) acc[oo] = b3[ob + oo];
        #pragma unroll 1
        for (int eb = 0; eb < 8; ++eb) {
            float hreg[8];
            #pragma unroll
            for (int j = 0; j < 8; ++j) hreg[j] = Abuf[p][eb * 8 + j];
            #pragma unroll
            for (int j = 0; j < 8; ++j) {
                const float* wr = W3 + (eb * 8 + j) * 64 + ob;
                #pragma unroll
                for (int oo = 0; oo < 16; ++oo) acc[oo] += hreg[j] * wr[oo];
            }
        }
        #pragma unroll
        for (int oo = 0; oo < 16; ++oo) Bbuf[p][ob + oo] = __sinf(freq[ob + oo] * acc[oo]);
    }
    __syncthreads();

    // out projection + decay, read B, write k[d][l]. Wave owns 32 channels.
    {
        const float t = (float)gp / 8191.0f;
        const float mind  = -3.0701134573253940f;    // log(0.01)/1.5
        const float dstep = -0.012004353694331942f;  // (log(.01)/.3 - log(.01)/1.5)/1023
        const int dd0 = blockIdx.y * 128 + g4 * 32;

        float acc[32];
        #pragma unroll
        for (int ii = 0; ii < 32; ++ii) acc[ii] = 0.0f;

        #pragma unroll 1
        for (int eb = 0; eb < 16; ++eb) {
            float hreg[4];
            #pragma unroll
            for (int j = 0; j < 4; ++j) hreg[j] = Bbuf[p][eb * 4 + j];
            #pragma unroll
            for (int j = 0; j < 4; ++j) {
                const float* wr = Wout + (eb * 4 + j) * 1024 + dd0;  // wave-uniform
                #pragma unroll
                for (int ii = 0; ii < 32; ++ii) acc[ii] += hreg[j] * wr[ii];
            }
        }
        #pragma unroll
        for (int ii = 0; ii < 32; ++ii) {
            int dd = dd0 + ii;
            float delta = fabsf(mind + dstep * (float)dd);
            kout[(size_t)dd * LSEQ + gp] = acc[ii] * __expf(-t * delta);
        }
    }
}

// ---------------------------------------------------------------------------
// Kernel 2: per-channel FFT causal convolution + skip. 1024 threads/block.
// LDS padded to 96 KB: forces 1 block/CU -> compiler VGPR budget 128 -> no
// spill. (At 64 KB the backend targeted 2 blocks/CU = 64 VGPR and spilled.)
// ---------------------------------------------------------------------------
__global__ void __launch_bounds__(1024) hyena_conv_k(
    const float* __restrict__ x, const float* kin,
    const float* __restrict__ Dvec, float* out)
{
    __shared__ float2 s[NC + 4096];              // 96 KB (FFT uses [0,NC))
    const int tid = threadIdx.x;
    const int d = blockIdx.x;
    const float Dd = Dvec[d];
    const float invN = 1.0f / 16384.0f;

    // ---- phase A: FFT of filter k[d], unpack spectrum into registers ----
    fwd_fft(s, tid, (const float2*)(kin + (size_t)d * LSEQ));
    __syncthreads();

    float2 Kk0, Kk1, Kk2, Kk3, Km0, Km1, Km2, Km3;  // K[k]/N, K[8192-k]/N
    if (tid == 0) {
        float2 C0 = s[0];                       // sw(0)==0
        Kk0 = make_float2((C0.x + C0.y) * invN, (C0.x - C0.y) * invN); // (K[0],K[8192])/N
        float2 C = s[1];                        // C[4096] at rev13(4096)=1, sw(1)==1
        Km0 = make_float2(C.x * invN, -C.y * invN);                    // conj(C)/N
    } else {
        k_unpack(s, tid, invN, Kk0, Km0);
    }
    k_unpack(s, tid + 1024, invN, Kk1, Km1);
    k_unpack(s, tid + 2048, invN, Kk2, Km2);
    k_unpack(s, tid + 3072, invN, Kk3, Km3);

    // ---- per-batch: FFT(x) -> multiply -> IFFT (+ x*D fused) ----
    for (int b = 0; b < 2; ++b) {
        __syncthreads();   // prior readers of s are done
        const size_t base = ((size_t)b * D_MODEL + d) * LSEQ;
        fwd_fft(s, tid, (const float2*)(x + base));
        __syncthreads();

        // unpack U, multiply by filter spectrum, repack Z2 (x2 folded in)
        if (tid == 0) {
            float2 C0 = s[0];
            float U0 = C0.x + C0.y, UN = C0.x - C0.y;   // U[0], U[8192] (real)
            float Y0 = U0 * Kk0.x, YN = UN * Kk0.y;
            s[0] = make_float2(Y0 + YN, Y0 - YN);       // Z2[0]
            float2 C = s[1];                            // C[4096]
            float2 U = make_float2(C.x, -C.y);          // U[4096] = conj(C)
            float2 Y = cmulf(U, Km0);
            s[1] = make_float2(2.0f * Y.x, -2.0f * Y.y); // Z2[4096] = 2*conj(Y)
        } else {
            mul_one(s, tid, Kk0, Km0);
        }
        mul_one(s, tid + 1024, Kk1, Km1);
        mul_one(s, tid + 2048, Kk2, Km2);
        mul_one(s, tid + 3072, Kk3, Km3);
        __syncthreads();

        // inverse: levels 1,2,4,8 in contiguous 16-blocks (const twiddles)
        if (tid < 512) {
            int b16 = tid << 4;
            float2 v[16];
            #pragma unroll
            for (int m = 0; m < 16; ++m) v[m] = s[sw(b16 + m)];
            dit16(v);
            #pragma unroll
            for (int m = 0; m < 16; ++m) s[sw(b16 + m)] = v[m];
        }
        __syncthreads();
        inv_pass8<16>(s, tid);
        __syncthreads();
        inv_pass8<128>(s, tid);
        __syncthreads();
        inv_last_out(s, tid, (const float2*)(x + base), (float2*)(out + base), Dd);
    }
}

extern "C" void kernel_launch(void* const* d_in, const int* in_sizes, int n_in,
                              void* d_out, int out_size, void* d_ws, size_t ws_size,
                              hipStream_t stream) {
    (void)in_sizes; (void)n_in; (void)out_size; (void)d_ws; (void)ws_size;
    const float* x    = (const float*)d_in[0];
    // d_in[1] is L (int scalar) -- constants are hardcoded (L=8192)
    const float* W1   = (const float*)d_in[2];
    const float* b1   = (const float*)d_in[3];
    const float* freq = (const float*)d_in[4];
    const float* W2   = (const float*)d_in[5];
    const float* b2   = (const float*)d_in[6];
    const float* W3   = (const float*)d_in[7];
    const float* b3   = (const float*)d_in[8];
    const float* Wout = (const float*)d_in[9];
    const float* Dv   = (const float*)d_in[10];
    float* out = (float*)d_out;

    // Time-domain filter k[1024][8192] lives in the b=0 half of d_out:
    // conv block d is the sole reader of k[d] and the sole (later) writer
    // of out[0][d] -- no cross-block hazard, no workspace needed.
    float* kbuf = out;

    hipLaunchKernelGGL(hyena_filter_k, dim3(128, 8), dim3(256), 0, stream,
                       W1, b1, freq, W2, b2, W3, b3, Wout, kbuf);
    hipLaunchKernelGGL(hyena_conv_k, dim3(1024), dim3(1024), 0, stream,
                       x, kbuf, Dv, out);
}

// Round 11
// 335.484 us; speedup vs baseline: 2.1707x; 2.1707x over previous
//
#include <hip/hip_runtime.h>

#define D_MODEL 1024
#define LSEQ    8192
#define NC      8192            // complex FFT size = (2*L)/2
#define PI_F    3.14159265358979323846f
#define TWO_PI_OVER_N 3.8349519697141029e-4f   // 2*pi/16384
#define R2F  0.70710678118654752440f           // cos(pi/4)
#define C18F 0.92387953251128675613f           // cos(pi/8)
#define S18F 0.38268343236508977173f           // sin(pi/8)

// Extended XOR swizzle on LDS float2 index (bijective on [0,8192)).
__device__ __forceinline__ int sw(int p) { return p ^ ((p >> 7) & 15) ^ ((p >> 3) & 7); }
__device__ __forceinline__ int rev13(int x) { return (int)(__brev((unsigned)x) >> 19); }
__device__ __forceinline__ float2 cmulf(float2 a, float2 b) {
    return make_float2(a.x*b.x - a.y*b.y, a.x*b.y + a.y*b.x);
}

// ---- radix-2 butterflies -------------------------------------------------
__device__ __forceinline__ void bf_dif(float2& a, float2& b, float c, float s) {
    float tx = a.x - b.x, ty = a.y - b.y;
    a.x += b.x; a.y += b.y;
    b.x = tx*c - ty*s; b.y = tx*s + ty*c;
}
__device__ __forceinline__ void bf_dif1(float2& a, float2& b) {        // w = 1
    float tx = a.x - b.x, ty = a.y - b.y;
    a.x += b.x; a.y += b.y;
    b.x = tx; b.y = ty;
}
__device__ __forceinline__ void bf_dif_mi(float2& a, float2& b) {      // w = -i
    float tx = a.x - b.x, ty = a.y - b.y;
    a.x += b.x; a.y += b.y;
    b.x = ty; b.y = -tx;
}
__device__ __forceinline__ void bf_dit(float2& a, float2& b, float c, float s) {
    float bx = b.x*c - b.y*s, by = b.x*s + b.y*c;
    b.x = a.x - bx; b.y = a.y - by;
    a.x += bx; a.y += by;
}
__device__ __forceinline__ void bf_dit1(float2& a, float2& b) {        // w = 1
    float bx = b.x, by = b.y;
    b.x = a.x - bx; b.y = a.y - by;
    a.x += bx; a.y += by;
}
__device__ __forceinline__ void bf_dit_pi(float2& a, float2& b) {      // w = +i
    float bx = -b.y, by = b.x;
    b.x = a.x - bx; b.y = a.y - by;
    a.x += bx; a.y += by;
}
// DIT a-output only: a' = a + w*b   (final level where b' is dead)
__device__ __forceinline__ void bf_dit_a(float2& a, float2 b, float c, float s) {
    a.x += b.x*c - b.y*s; a.y += b.x*s + b.y*c;
}

// === conv kernel: 512 threads (8 waves). Empirical VGPR-budget law across ==
// === r3-r10: budget = 1024/wavesPerWG (compiler assumes 2 WGs/CU, ignores ==
// === LDS and attributes). 1024thr -> 64 regs -> ~2GB spill; 256thr -> 256. =
// === 512thr -> 128-reg budget; peak live demand here ~80 -> NO spill, and ==
// === 8-wave blocks give 2-4 waves/SIMD residency (4x the r4 structure). ====

// ---- fused forward pass: DIF levels H, H/2, H/4 (H in {512, 64}) ---------
template<int H>
__device__ __forceinline__ void fwd_pass8(float2* s, int gi) {
    const float astep = -PI_F / (float)H;
    int q    = gi & (H/4 - 1);
    int base = (gi - q) * 8 + q;                // block*2H + q
    float2 v[8];
    #pragma unroll
    for (int m = 0; m < 8; ++m) v[m] = s[sw(base + m*(H/4))];
    float a = astep * (float)q;
    float c1,s1,c2,s2,c4,s4;
    __sincosf(a,     &s1, &c1);
    __sincosf(a+a,   &s2, &c2);
    __sincosf(4.f*a, &s4, &c4);
    // level H: pairs (m, m+4), w = e^{ia} * e^{-i pi m/4}
    bf_dif(v[0], v[4], c1, s1);
    bf_dif(v[1], v[5], R2F*(c1+s1), R2F*(s1-c1));
    bf_dif(v[2], v[6], s1, -c1);
    bf_dif(v[3], v[7], R2F*(s1-c1), -R2F*(c1+s1));
    // level H/2: pairs (m, m+2); odd pairs get extra *(-i)
    bf_dif(v[0], v[2], c2, s2);  bf_dif(v[4], v[6], c2, s2);
    bf_dif(v[1], v[3], s2, -c2); bf_dif(v[5], v[7], s2, -c2);
    // level H/4: all pairs (m, m+1), w = e^{i4a}
    bf_dif(v[0], v[1], c4, s4); bf_dif(v[2], v[3], c4, s4);
    bf_dif(v[4], v[5], c4, s4); bf_dif(v[6], v[7], c4, s4);
    #pragma unroll
    for (int m = 0; m < 8; ++m) s[sw(base + m*(H/4))] = v[m];
}

// ---- DIF levels 8,4,2,1 on a contiguous 16-block (all twiddles const) ----
__device__ __forceinline__ void dif16(float2* v) {
    bf_dif1 (v[0], v[8]);
    bf_dif  (v[1], v[9],   C18F, -S18F);
    bf_dif  (v[2], v[10],  R2F,  -R2F);
    bf_dif  (v[3], v[11],  S18F, -C18F);
    bf_dif_mi(v[4], v[12]);
    bf_dif  (v[5], v[13], -S18F, -C18F);
    bf_dif  (v[6], v[14], -R2F,  -R2F);
    bf_dif  (v[7], v[15], -C18F, -S18F);
    bf_dif1 (v[0], v[4]);              bf_dif1 (v[8],  v[12]);
    bf_dif  (v[1], v[5],  R2F, -R2F);  bf_dif  (v[9],  v[13],  R2F, -R2F);
    bf_dif_mi(v[2], v[6]);             bf_dif_mi(v[10], v[14]);
    bf_dif  (v[3], v[7], -R2F, -R2F);  bf_dif  (v[11], v[15], -R2F, -R2F);
    bf_dif1 (v[0], v[2]); bf_dif1 (v[4], v[6]); bf_dif1 (v[8], v[10]); bf_dif1 (v[12], v[14]);
    bf_dif_mi(v[1], v[3]); bf_dif_mi(v[5], v[7]); bf_dif_mi(v[9], v[11]); bf_dif_mi(v[13], v[15]);
    bf_dif1(v[0], v[1]); bf_dif1(v[2], v[3]);  bf_dif1(v[4], v[5]);  bf_dif1(v[6], v[7]);
    bf_dif1(v[8], v[9]); bf_dif1(v[10],v[11]); bf_dif1(v[12],v[13]); bf_dif1(v[14],v[15]);
}

// ---- full forward FFT: global (zero-padded) -> LDS, bit-reversed output --
// 512 threads: pass1 and radix-8 passes run 2 groups/thread (unroll 1);
// dif16 runs exactly 1 contiguous 16-block per thread (all threads active).
__device__ __forceinline__ void fwd_fft(float2* s, int tid, const float2* __restrict__ g) {
    {
        const float astep = -PI_F / 4096.0f;
        #pragma unroll 1
        for (int it = 0; it < 2; ++it) {
            int q = tid + it * 512;             // 0..1023
            float2 v[8];
            #pragma unroll
            for (int m = 0; m < 4; ++m) v[m] = g[q + m*1024];
            float a = astep * (float)q;
            float c1,s1,c2,s2,c4,s4;
            __sincosf(a,     &s1, &c1);
            __sincosf(a+a,   &s2, &c2);
            __sincosf(4.f*a, &s4, &c4);
            // level 4096 vs zero upper half: v[m+4] = v[m] * (e^{ia} e^{-i pi m/4})
            float wc, ws;
            wc = c1;            ws = s1;             v[4] = make_float2(v[0].x*wc - v[0].y*ws, v[0].x*ws + v[0].y*wc);
            wc = R2F*(c1+s1);   ws = R2F*(s1-c1);    v[5] = make_float2(v[1].x*wc - v[1].y*ws, v[1].x*ws + v[1].y*wc);
            wc = s1;            ws = -c1;            v[6] = make_float2(v[2].x*wc - v[2].y*ws, v[2].x*ws + v[2].y*wc);
            wc = R2F*(s1-c1);   ws = -R2F*(c1+s1);   v[7] = make_float2(v[3].x*wc - v[3].y*ws, v[3].x*ws + v[3].y*wc);
            // level 2048
            bf_dif(v[0], v[2], c2, s2);  bf_dif(v[4], v[6], c2, s2);
            bf_dif(v[1], v[3], s2, -c2); bf_dif(v[5], v[7], s2, -c2);
            // level 1024
            bf_dif(v[0], v[1], c4, s4); bf_dif(v[2], v[3], c4, s4);
            bf_dif(v[4], v[5], c4, s4); bf_dif(v[6], v[7], c4, s4);
            #pragma unroll
            for (int m = 0; m < 8; ++m) s[sw(q + m*1024)] = v[m];
        }
    }
    __syncthreads();
    #pragma unroll 1
    for (int it = 0; it < 2; ++it) fwd_pass8<512>(s, tid + it * 512);
    __syncthreads();
    #pragma unroll 1
    for (int it = 0; it < 2; ++it) fwd_pass8<64>(s, tid + it * 512);
    __syncthreads();
    {                                           // levels 8,4,2,1 (16/thread)
        int base = tid << 4;
        float2 v[16];
        #pragma unroll
        for (int m = 0; m < 16; ++m) v[m] = s[sw(base + m)];
        dif16(v);
        #pragma unroll
        for (int m = 0; m < 16; ++m) s[sw(base + m)] = v[m];
    }
}

// ---- DIT levels 1,2,4,8 on a contiguous 16-block (const twiddles, +i) ----
__device__ __forceinline__ void dit16(float2* v) {
    bf_dit1(v[0], v[1]); bf_dit1(v[2], v[3]);  bf_dit1(v[4], v[5]);  bf_dit1(v[6], v[7]);
    bf_dit1(v[8], v[9]); bf_dit1(v[10],v[11]); bf_dit1(v[12],v[13]); bf_dit1(v[14],v[15]);
    bf_dit1 (v[0], v[2]); bf_dit_pi(v[1], v[3]);
    bf_dit1 (v[4], v[6]); bf_dit_pi(v[5], v[7]);
    bf_dit1 (v[8], v[10]); bf_dit_pi(v[9], v[11]);
    bf_dit1 (v[12],v[14]); bf_dit_pi(v[13],v[15]);
    bf_dit1 (v[0], v[4]);             bf_dit1 (v[8],  v[12]);
    bf_dit  (v[1], v[5],  R2F, R2F);  bf_dit  (v[9],  v[13],  R2F, R2F);
    bf_dit_pi(v[2], v[6]);            bf_dit_pi(v[10], v[14]);
    bf_dit  (v[3], v[7], -R2F, R2F);  bf_dit  (v[11], v[15], -R2F, R2F);
    bf_dit1 (v[0], v[8]);
    bf_dit  (v[1], v[9],   C18F, S18F);
    bf_dit  (v[2], v[10],  R2F,  R2F);
    bf_dit  (v[3], v[11],  S18F, C18F);
    bf_dit_pi(v[4], v[12]);
    bf_dit  (v[5], v[13], -S18F, C18F);
    bf_dit  (v[6], v[14], -R2F,  R2F);
    bf_dit  (v[7], v[15], -C18F, S18F);
}

// ---- fused inverse pass: DIT levels H, 2H, 4H (H in {16, 128}) -----------
template<int H>
__device__ __forceinline__ void inv_pass8(float2* s, int gi) {
    const float bstep = PI_F / (float)(4*H);
    int q    = gi & (H - 1);
    int base = (gi - q) * 8 + q;                // block*8H + q
    float2 v[8];
    #pragma unroll
    for (int m = 0; m < 8; ++m) v[m] = s[sw(base + m*H)];
    float bb = bstep * (float)q;
    float cb,sb,c2,s2,c4,s4;
    __sincosf(bb,      &sb, &cb);
    __sincosf(bb+bb,   &s2, &c2);
    __sincosf(4.f*bb,  &s4, &c4);
    bf_dit(v[0],v[1],c4,s4); bf_dit(v[2],v[3],c4,s4);
    bf_dit(v[4],v[5],c4,s4); bf_dit(v[6],v[7],c4,s4);
    bf_dit(v[0],v[2], c2,s2);  bf_dit(v[4],v[6], c2,s2);
    bf_dit(v[1],v[3],-s2,c2);  bf_dit(v[5],v[7],-s2,c2);
    bf_dit(v[0],v[4],  cb, sb);
    bf_dit(v[1],v[5],  R2F*(cb-sb), R2F*(sb+cb));
    bf_dit(v[2],v[6], -sb, cb);
    bf_dit(v[3],v[7], -R2F*(sb+cb), R2F*(cb-sb));
    #pragma unroll
    for (int m = 0; m < 8; ++m) s[sw(base + m*H)] = v[m];
}

// ---- last inverse pass (levels 1024,2048,4096) fused with epilogue -------
// Only complex n in [0,4096) survive (= m 0..3); store MUST stop at m<4.
__device__ __forceinline__ void inv_last_out(const float2* s, int gi,
                                             const float2* __restrict__ xv,
                                             float2* __restrict__ ov, float Dd) {
    const float bstep = PI_F / 4096.0f;
    int q = gi;                                 // single 8192-block
    float2 v[8];
    #pragma unroll
    for (int m = 0; m < 8; ++m) v[m] = s[sw(q + m*1024)];
    float bb = bstep * (float)q;
    float cb,sb,c2,s2,c4,s4;
    __sincosf(bb,      &sb, &cb);
    __sincosf(bb+bb,   &s2, &c2);
    __sincosf(4.f*bb,  &s4, &c4);
    bf_dit(v[0],v[1],c4,s4); bf_dit(v[2],v[3],c4,s4);
    bf_dit(v[4],v[5],c4,s4); bf_dit(v[6],v[7],c4,s4);
    bf_dit(v[0],v[2], c2,s2);  bf_dit(v[4],v[6], c2,s2);
    bf_dit(v[1],v[3],-s2,c2);  bf_dit(v[5],v[7],-s2,c2);
    bf_dit_a(v[0], v[4],  cb, sb);
    bf_dit_a(v[1], v[5],  R2F*(cb-sb), R2F*(sb+cb));
    bf_dit_a(v[2], v[6], -sb, cb);
    bf_dit_a(v[3], v[7], -R2F*(sb+cb), R2F*(cb-sb));
    #pragma unroll
    for (int m = 0; m < 4; ++m) {
        int n = q + m*1024;
        float2 xx = xv[n];
        ov[n] = make_float2(v[m].x + xx.x * Dd, v[m].y + xx.y * Dd);
    }
}

// ---- spectral helpers ----------------------------------------------------
__device__ __forceinline__ void k_unpack(const float2* s, int k, float invN,
                                         float2& Kkj, float2& Kmj) {
    int m = NC - k;
    float2 Ck = s[sw(rev13(k))], Cm = s[sw(rev13(m))];
    float sn, cs;
    __sincosf(TWO_PI_OVER_N * (float)k, &sn, &cs);   // w = (cs,-sn)
    float2 E = make_float2(Ck.x + Cm.x, Ck.y - Cm.y); // Ck + conj(Cm)
    float2 O = make_float2(Ck.x - Cm.x, Ck.y + Cm.y); // Ck - conj(Cm)
    float2 WO = make_float2(O.x * cs + O.y * sn, -O.x * sn + O.y * cs); // w*O
    float2 T = make_float2(-WO.y, WO.x);              // i*w*O
    Kkj = make_float2(0.5f * invN * (E.x - T.x),  0.5f * invN * (E.y - T.y));
    Kmj = make_float2(0.5f * invN * (E.x + T.x), -0.5f * invN * (E.y + T.y)); // conj(E+T)/2N
}

__device__ __forceinline__ void mul_one(float2* s, int k, float2 Kkj, float2 Kmj) {
    int m = NC - k;
    int pk = sw(rev13(k)), pm = sw(rev13(m));
    float2 Ck = s[pk], Cm = s[pm];
    float sn, cs;
    __sincosf(TWO_PI_OVER_N * (float)k, &sn, &cs);   // w = (cs,-sn)
    float2 E = make_float2(Ck.x + Cm.x, Ck.y - Cm.y);
    float2 O = make_float2(Ck.x - Cm.x, Ck.y + Cm.y);
    float2 WO = make_float2(O.x * cs + O.y * sn, -O.x * sn + O.y * cs);
    float2 T = make_float2(-WO.y, WO.x);
    float2 Uk = make_float2(0.5f * (E.x - T.x),  0.5f * (E.y - T.y));
    float2 Um = make_float2(0.5f * (E.x + T.x), -0.5f * (E.y + T.y));
    float2 Yk = cmulf(Uk, Kkj);
    float2 Ym = cmulf(Um, Kmj);
    float2 P = make_float2(Yk.x + Ym.x, Yk.y - Ym.y);  // Yk + conj(Ym)
    float2 Q = make_float2(Yk.x - Ym.x, Yk.y + Ym.y);  // Yk - conj(Ym)
    float2 CQ = make_float2(Q.x * cs - Q.y * sn, Q.x * sn + Q.y * cs); // conj(w)*Q
    float2 T2 = make_float2(-CQ.y, CQ.x);              // i*conj(w)*Q
    s[pk] = make_float2(P.x + T2.x, P.y + T2.y);       // Z2[k]
    s[pm] = make_float2(P.x - T2.x, -(P.y - T2.y));    // Z2[m] = conj(P-T2)
}

// ---------------------------------------------------------------------------
// Kernel 1: implicit-filter MLP + output projection + exponential modulation.
// zbuf phase-0 (trig amortized) folded into an A/B ping-pong; batched LDS
// reads; (256,4) caps VGPR at 128; 33.3 KB LDS -> 4 blocks/CU. (Verified.)
// ---------------------------------------------------------------------------
__global__ void __launch_bounds__(256, 4) hyena_filter_k(
    const float* __restrict__ W1, const float* __restrict__ b1,
    const float* __restrict__ freq,
    const float* __restrict__ W2, const float* __restrict__ b2,
    const float* __restrict__ W3, const float* __restrict__ b3,
    const float* __restrict__ Wout,
    float* __restrict__ kout)
{
    __shared__ float Abuf[64][65];   // stride 65: (p+o)%32 -> 2-way (free)
    __shared__ float Bbuf[64][65];

    const int tid = threadIdx.x;
    const int pbase = blockIdx.x * 64;

    // phase 0: positional embedding z[p][0..32] -> Abuf (trig amortized)
    for (int idx = tid; idx < 64 * 33; idx += 256) {
        int p = idx & 63, e = idx >> 6;
        int gp = pbase + p;
        float w = 7.6699039394282907e-4f * (float)gp;   // 2*pi*gp/8192
        float val;
        if (e == 0) {
            val = (float)gp / 8191.0f;
        } else if (e < 17) {
            float f = 1.0e-4f + (float)(e - 1) * ((15.0f - 1.0e-4f) / 15.0f);
            val = cosf(f * w);
        } else {
            float f = 1.0e-4f + (float)(e - 17) * ((15.0f - 1.0e-4f) / 15.0f);
            val = -sinf(f * w);
        }
        Abuf[p][e] = val;
    }
    __syncthreads();

    const int p  = tid & 63;                                       // lane-varying
    const int g4 = __builtin_amdgcn_readfirstlane(tid >> 6);       // wave-uniform
    const int ob = g4 * 16;
    const int gp = pbase + p;

    // layer 1: 33 -> 64, A -> B
    {
        float acc[16];
        #pragma unroll
        for (int oo = 0; oo < 16; ++oo) acc[oo] = b1[ob + oo];
        #pragma unroll
        for (int e = 0; e < 33; ++e) {
            float ae = Abuf[p][e];
            const float* wr = W1 + e * 64 + ob;
            #pragma unroll
            for (int oo = 0; oo < 16; ++oo) acc[oo] += ae * wr[oo];
        }
        #pragma unroll
        for (int oo = 0; oo < 16; ++oo) Bbuf[p][ob + oo] = __sinf(freq[ob + oo] * acc[oo]);
    }
    __syncthreads();
    // layer 2: B -> A (old A dead after the L1 barrier)
    {
        float acc[16];
        #pragma unroll
        for (int oo = 0; oo < 16; ++oo) acc[oo] = b2[ob + oo];
        #pragma unroll 1
        for (int eb = 0; eb < 8; ++eb) {
            float hreg[8];
            #pragma unroll
            for (int j = 0; j < 8; ++j) hreg[j] = Bbuf[p][eb * 8 + j];
            #pragma unroll
            for (int j = 0; j < 8; ++j) {
                const float* wr = W2 + (eb * 8 + j) * 64 + ob;
                #pragma unroll
                for (int oo = 0; oo < 16; ++oo) acc[oo] += hreg[j] * wr[oo];
            }
        }
        #pragma unroll
        for (int oo = 0; oo < 16; ++oo) Abuf[p][ob + oo] = __sinf(freq[ob + oo] * acc[oo]);
    }
    __syncthreads();
    // layer 3: A -> B
    {
        float acc[16];
        #pragma unroll
        for (int oo = 0; oo < 16; ++oo) acc[oo] = b3[ob + oo];
        #pragma unroll 1
        for (int eb = 0; eb < 8; ++eb) {
            float hreg[8];
            #pragma unroll
            for (int j = 0; j < 8; ++j) hreg[j] = Abuf[p][eb * 8 + j];
            #pragma unroll
            for (int j = 0; j < 8; ++j) {
                const float* wr = W3 + (eb * 8 + j) * 64 + ob;
                #pragma unroll
                for (int oo = 0; oo < 16; ++oo) acc[oo] += hreg[j] * wr[oo];
            }
        }
        #pragma unroll
        for (int oo = 0; oo < 16; ++oo) Bbuf[p][ob + oo] = __sinf(freq[ob + oo] * acc[oo]);
    }
    __syncthreads();

    // out projection + decay, read B, write k[d][l]. Wave owns 32 channels.
    {
        const float t = (float)gp / 8191.0f;
        const float mind  = -3.0701134573253940f;    // log(0.01)/1.5
        const float dstep = -0.012004353694331942f;  // (log(.01)/.3 - log(.01)/1.5)/1023
        const int dd0 = blockIdx.y * 128 + g4 * 32;

        float acc[32];
        #pragma unroll
        for (int ii = 0; ii < 32; ++ii) acc[ii] = 0.0f;

        #pragma unroll 1
        for (int eb = 0; eb < 16; ++eb) {
            float hreg[4];
            #pragma unroll
            for (int j = 0; j < 4; ++j) hreg[j] = Bbuf[p][eb * 4 + j];
            #pragma unroll
            for (int j = 0; j < 4; ++j) {
                const float* wr = Wout + (eb * 4 + j) * 1024 + dd0;  // wave-uniform
                #pragma unroll
                for (int ii = 0; ii < 32; ++ii) acc[ii] += hreg[j] * wr[ii];
            }
        }
        #pragma unroll
        for (int ii = 0; ii < 32; ++ii) {
            int dd = dd0 + ii;
            float delta = fabsf(mind + dstep * (float)dd);
            kout[(size_t)dd * LSEQ + gp] = acc[ii] * __expf(-t * delta);
        }
    }
}

// ---------------------------------------------------------------------------
// Kernel 2: per-channel FFT causal convolution + skip. 512 threads/block:
// 8 waves -> 128-VGPR budget (empirical law: 1024/wavesPerWG) -> no spill;
// 64 KB LDS -> up to 2 blocks/CU = 4 waves/SIMD resident.
// ---------------------------------------------------------------------------
__global__ void __launch_bounds__(512) hyena_conv_k(
    const float* __restrict__ x, const float* kin,
    const float* __restrict__ Dvec, float* out)
{
    __shared__ float2 s[NC];                     // 64 KB
    const int tid = threadIdx.x;
    const int d = blockIdx.x;
    const float Dd = Dvec[d];
    const float invN = 1.0f / 16384.0f;

    // ---- phase A: FFT of filter k[d], unpack spectrum into registers ----
    fwd_fft(s, tid, (const float2*)(kin + (size_t)d * LSEQ));
    __syncthreads();

    float2 Kk[8], Km[8];       // K[k]/N and K[8192-k]/N for k = tid + j*512
    #pragma unroll
    for (int j = 0; j < 8; ++j) {
        int k = tid + j * 512;
        if (j == 0 && tid == 0) {
            float2 C0 = s[0];                   // sw(0)==0
            Kk[0] = make_float2((C0.x + C0.y) * invN, (C0.x - C0.y) * invN); // (K[0],K[8192])/N
            float2 C = s[1];                    // C[4096] at rev13(4096)=1, sw(1)==1
            Km[0] = make_float2(C.x * invN, -C.y * invN);                    // conj(C)/N
        } else {
            k_unpack(s, k, invN, Kk[j], Km[j]);
        }
    }

    // ---- per-batch: FFT(x) -> multiply -> IFFT (+ x*D fused) ----
    for (int b = 0; b < 2; ++b) {
        __syncthreads();   // prior readers of s are done
        const size_t base = ((size_t)b * D_MODEL + d) * LSEQ;
        fwd_fft(s, tid, (const float2*)(x + base));
        __syncthreads();

        // unpack U, multiply by filter spectrum, repack Z2 (x2 folded in)
        #pragma unroll
        for (int j = 0; j < 8; ++j) {
            int k = tid + j * 512;
            if (j == 0 && tid == 0) {
                float2 C0 = s[0];
                float U0 = C0.x + C0.y, UN = C0.x - C0.y;   // U[0], U[8192] (real)
                float Y0 = U0 * Kk[0].x, YN = UN * Kk[0].y;
                s[0] = make_float2(Y0 + YN, Y0 - YN);       // Z2[0]
                float2 C = s[1];                            // C[4096]
                float2 U = make_float2(C.x, -C.y);          // U[4096] = conj(C)
                float2 Y = cmulf(U, Km[0]);
                s[1] = make_float2(2.0f * Y.x, -2.0f * Y.y); // Z2[4096] = 2*conj(Y)
            } else {
                mul_one(s, k, Kk[j], Km[j]);
            }
        }
        __syncthreads();

        // inverse: levels 1,2,4,8 in contiguous 16-blocks (const twiddles)
        {
            int b16 = tid << 4;
            float2 v[16];
            #pragma unroll
            for (int m = 0; m < 16; ++m) v[m] = s[sw(b16 + m)];
            dit16(v);
            #pragma unroll
            for (int m = 0; m < 16; ++m) s[sw(b16 + m)] = v[m];
        }
        __syncthreads();
        #pragma unroll 1
        for (int it = 0; it < 2; ++it) inv_pass8<16>(s, tid + it * 512);
        __syncthreads();
        #pragma unroll 1
        for (int it = 0; it < 2; ++it) inv_pass8<128>(s, tid + it * 512);
        __syncthreads();
        #pragma unroll 1
        for (int it = 0; it < 2; ++it)
            inv_last_out(s, tid + it * 512, (const float2*)(x + base),
                         (float2*)(out + base), Dd);
    }
}

extern "C" void kernel_launch(void* const* d_in, const int* in_sizes, int n_in,
                              void* d_out, int out_size, void* d_ws, size_t ws_size,
                              hipStream_t stream) {
    (void)in_sizes; (void)n_in; (void)out_size; (void)d_ws; (void)ws_size;
    const float* x    = (const float*)d_in[0];
    // d_in[1] is L (int scalar) -- constants are hardcoded (L=8192)
    const float* W1   = (const float*)d_in[2];
    const float* b1   = (const float*)d_in[3];
    const float* freq = (const float*)d_in[4];
    const float* W2   = (const float*)d_in[5];
    const float* b2   = (const float*)d_in[6];
    const float* W3   = (const float*)d_in[7];
    const float* b3   = (const float*)d_in[8];
    const float* Wout = (const float*)d_in[9];
    const float* Dv   = (const float*)d_in[10];
    float* out = (float*)d_out;

    // Time-domain filter k[1024][8192] lives in the b=0 half of d_out:
    // conv block d is the sole reader of k[d] and the sole (later) writer
    // of out[0][d] -- no cross-block hazard, no workspace needed.
    float* kbuf = out;

    hipLaunchKernelGGL(hyena_filter_k, dim3(128, 8), dim3(256), 0, stream,
                       W1, b1, freq, W2, b2, W3, b3, Wout, kbuf);
    hipLaunchKernelGGL(hyena_conv_k, dim3(1024), dim3(512), 0, stream,
                       x, kbuf, Dv, out);
}